// Round 1
// baseline (259.665 us; speedup 1.0000x reference)
//
#include <hip/hip_runtime.h>

// Depthwise 3D Gaussian conv, 5x5x5, SAME, fp32.
// x: (2,16,64,128,128) NCDHW; weight: (16,1,5,5,5).
// Strategy: the Gaussian is exactly separable -> derive 1D marginals on
// device and do fused z/y/x 5-tap passes in one kernel:
//   - per z-slice: stage halo'd rows to LDS (float4), y-pass to LDS,
//     x-pass per-thread, z-pass via 5-deep register ring.
// Memory-bound: compulsory 256 MiB -> ~41 us floor at 6.3 TB/s.

#define DD 64
#define HH 128
#define WW 128
#define TH 8          // H rows per block
#define NC 16         // channels
#define PITCH 136     // LDS row pitch (floats): x in [-4, 131], halo zeros
#define RAWROWS 12    // TH + 4
#define XOFF 4        // LDS col of x=0
#define ZCHUNK 32     // z outputs per block

__global__ __launch_bounds__(256, 4)
void gauss3d_sep_kernel(const float* __restrict__ x,
                        const float* __restrict__ wt,
                        float* __restrict__ out)
{
    __shared__ float raw[RAWROWS][PITCH];  // current input slice rows (halo'd)
    __shared__ float ybuf[TH][PITCH];      // y-convolved slice
    __shared__ float wlds[16];             // 1D weights: wz[5], wy[5], wx[5]

    const int tid   = threadIdx.x;
    const int ytile = blockIdx.x;            // 0..15
    const int slab  = blockIdx.y;            // 0..31 (n*16 + c)
    const int z0    = blockIdx.z * ZCHUNK;   // 0 or 32
    const int by    = ytile * TH;
    const int ch    = slab & (NC - 1);

    const float* xs = x   + (size_t)slab * DD * HH * WW;
    float*       os = out + (size_t)slab * DD * HH * WW;

    // Zero LDS once: halo cells stay zero forever (only interior rewritten).
    for (int i = tid; i < RAWROWS * PITCH; i += 256) (&raw[0][0])[i]  = 0.f;
    for (int i = tid; i < TH * PITCH;      i += 256) (&ybuf[0][0])[i] = 0.f;

    // Derive separable 1D factors as marginals of the (normalized) 3D weight.
    if (tid < 15) {
        const int a = tid / 5, q = tid % 5;     // a: 0=z,1=y,2=x
        const float* wp = wt + ch * 125;
        float s = 0.f;
        for (int u = 0; u < 5; ++u)
            for (int v = 0; v < 5; ++v) {
                const int i0 = (a == 0) ? q : u;
                const int j0 = (a == 1) ? q : ((a == 0) ? u : v);
                const int k0 = (a == 2) ? q : v;
                s += wp[i0 * 25 + j0 * 5 + k0];
            }
        wlds[a * 5 + q] = s;
    }
    __syncthreads();

    float wz[5], wy[5], wx[5];
#pragma unroll
    for (int i = 0; i < 5; ++i) { wz[i] = wlds[i]; wy[i] = wlds[5 + i]; wx[i] = wlds[10 + i]; }

    // Per-thread geometry: one (ty, x0..x0+3) column group, iterated over z.
    const int ty = tid >> 5;                // 0..7
    const int x0 = (tid & 31) << 2;         // 0,4,...,124

    // Staging assignment: thread loads raw rows r1 and r1+8 at f4 column cx4.
    const int  r1  = tid >> 5;
    const int  r2  = r1 + 8;
    const int  gy1 = by + r1 - 2;
    const int  gy2 = by + r2 - 2;
    const bool v1  = (gy1 >= 0) && (gy1 < HH);
    const bool v2  = (gy2 >= 0) && (gy2 < HH);
    const int  cx4 = (tid & 31) << 2;

    // 5-deep ring of 2D-convolved values S[z] for 4 columns (static indices).
    float ring[5][4];
#pragma unroll
    for (int i = 0; i < 5; ++i)
#pragma unroll
        for (int j = 0; j < 4; ++j) ring[i][j] = 0.f;

    auto ypass_chunk = [&](int cc) {
        const int row = cc / 34;                 // 0..7
        const int col = (cc - row * 34) << 2;    // 0..132, f4-aligned
        float4 acc = make_float4(0.f, 0.f, 0.f, 0.f);
#pragma unroll
        for (int dy = 0; dy < 5; ++dy) {
            const float4 rv = *(const float4*)&raw[row + dy][col];
            const float  w  = wy[dy];
            acc.x += w * rv.x; acc.y += w * rv.y;
            acc.z += w * rv.z; acc.w += w * rv.w;
        }
        *(float4*)&ybuf[row][col] = acc;
    };

    for (int zs = z0 - 2; zs < z0 + ZCHUNK + 2; ++zs) {
        float snew[4];
        if (zs >= 0 && zs < DD) {
            // 1. stage slice zs (interior only; halo cells remain zero)
            const float* sl = xs + (size_t)zs * HH * WW;
            if (v1) *(float4*)&raw[r1][XOFF + cx4] = *(const float4*)(sl + gy1 * WW + cx4);
            if (v2) *(float4*)&raw[r2][XOFF + cx4] = *(const float4*)(sl + gy2 * WW + cx4);
            __syncthreads();
            // 2. y-pass: 8 rows x 34 f4-chunks = 272 chunks
            ypass_chunk(tid);
            if (tid < 16) ypass_chunk(tid + 256);
            __syncthreads();
            // 3. x-pass: read ybuf[ty][x0-4 .. x0+7] (LDS cols x0..x0+11)
            const float4 a0 = *(const float4*)&ybuf[ty][x0];
            const float4 a1 = *(const float4*)&ybuf[ty][x0 + 4];
            const float4 a2 = *(const float4*)&ybuf[ty][x0 + 8];
            const float ya[12] = { a0.x, a0.y, a0.z, a0.w,
                                   a1.x, a1.y, a1.z, a1.w,
                                   a2.x, a2.y, a2.z, a2.w };
#pragma unroll
            for (int j = 0; j < 4; ++j) {
                float s = 0.f;
#pragma unroll
                for (int i = 0; i < 5; ++i) s += wx[i] * ya[j + i + 2];
                snew[j] = s;
            }
        } else {
#pragma unroll
            for (int j = 0; j < 4; ++j) snew[j] = 0.f;
        }

        // 4. rotate ring, push S[zs]
#pragma unroll
        for (int i = 0; i < 4; ++i)
#pragma unroll
            for (int j = 0; j < 4; ++j) ring[i][j] = ring[i + 1][j];
#pragma unroll
        for (int j = 0; j < 4; ++j) ring[4][j] = snew[j];

        // 5. z-pass: out[zs-2] = sum_k wz[k] * S[zs-4+k]
        const int zo = zs - 2;
        if (zo >= z0 && zo < z0 + ZCHUNK) {
            float4 o; o.x = o.y = o.z = o.w = 0.f;
#pragma unroll
            for (int k = 0; k < 5; ++k) {
                o.x += wz[k] * ring[k][0];
                o.y += wz[k] * ring[k][1];
                o.z += wz[k] * ring[k][2];
                o.w += wz[k] * ring[k][3];
            }
            *(float4*)(os + (size_t)zo * HH * WW + (size_t)(by + ty) * WW + x0) = o;
        }
    }
}

extern "C" void kernel_launch(void* const* d_in, const int* in_sizes, int n_in,
                              void* d_out, int out_size, void* d_ws, size_t ws_size,
                              hipStream_t stream)
{
    const float* x = (const float*)d_in[0];   // 2*16*64*128*128 fp32
    const float* w = (const float*)d_in[1];   // 16*125 fp32
    float*       o = (float*)d_out;           // same shape as x

    dim3 grid(HH / TH, 2 * NC, DD / ZCHUNK);  // (16, 32, 2) = 1024 blocks
    gauss3d_sep_kernel<<<grid, 256, 0, stream>>>(x, w, o);
}